// Round 2
// baseline (250.813 us; speedup 1.0000x reference)
//
#include <hip/hip_runtime.h>
#include <hip/hip_fp16.h>

#define N_NODES 50000
#define N_EDGES 800000
#define F_INN   128
#define F_HID   96
#define F_OUTT  40

// Feature-sliced T/H layout: 4 slices x 24 features. Slice s holds original
// features [24s, 24s+24) for ALL nodes, contiguously: 50000 x 48B = 2.4 MB
// per slice -> fits one XCD's 4MB L2. 24 = 3x8 so 8-feature GEMM chunks
// never cross a slice boundary.
#define SL_HALVES (N_NODES * 24)   // halves per slice  (1,200,000)
#define SL_F4     (N_NODES * 3)    // float4s per slice (150,000)
#define NGRP      3125             // 16-node groups per slice (50000/16)

typedef _Float16 half8 __attribute__((ext_vector_type(8)));
typedef float    floatx4 __attribute__((ext_vector_type(4)));

// ---------------------------------------------------------------------------
// MFMA GEMM body: T[n][96] (fp16, UNSCALED, SLICED layout) = X[n x FI] @ W.
// A = W^T tile (m=feature), B = node rows (n=node). 4 waves x 16 nodes = 64/blk.
// TIN = float (dense rows, load+cvt) or __half (sliced fp16 input).
// ---------------------------------------------------------------------------
template <int FI, typename TIN>
__device__ __forceinline__ void mfma_gemm_body(
        const TIN* __restrict__ X, const __half* __restrict__ BTg,
        float4* __restrict__ Th4, int n, int bx) {
    __shared__ __half BTl[96 * 136];          // 26112 B
    __shared__ __half OUTl[4 * 16 * 104];     // 13312 B
    int tid = threadIdx.x;
    {   // stage BT (1632 x 16B)
        const int4* s = reinterpret_cast<const int4*>(BTg);
        int4* d = reinterpret_cast<int4*>(BTl);
        for (int i = tid; i < 96 * 136 / 8; i += 256) d[i] = s[i];
    }
    __syncthreads();

    int lane = tid & 63, w = tid >> 6;
    int lm = lane & 15, q = lane >> 4;
    int base = bx * 64 + w * 16;
    int node = base + lm;
    int nclamp = min(node, n - 1);

    floatx4 cf[6];
    #pragma unroll
    for (int t = 0; t < 6; ++t) cf[t] = (floatx4){0.f, 0.f, 0.f, 0.f};

    constexpr int KS = FI / 32;
    #pragma unroll
    for (int ks = 0; ks < KS; ++ks) {
        // B-operand: lane holds k = 32*ks + q*8 .. +7 of this node's row
        half8 bv;
        if constexpr (sizeof(TIN) == 4) {
            const float4* xr = reinterpret_cast<const float4*>(
                X + (size_t)nclamp * FI + 32 * ks + q * 8);
            float4 f0 = xr[0], f1 = xr[1];
            union { half8 v; __half2 h[4]; } b;
            b.h[0] = __floats2half2_rn(f0.x, f0.y);
            b.h[1] = __floats2half2_rn(f0.z, f0.w);
            b.h[2] = __floats2half2_rn(f1.x, f1.y);
            b.h[3] = __floats2half2_rn(f1.z, f1.w);
            bv = b.v;
        } else {
            // sliced fp16 input: chunk c8 = 4*ks+q -> slice c8/3, offset c8%3
            int c8 = 4 * ks + q;
            int sl = c8 / 3, of8 = c8 - sl * 3;
            bv = *reinterpret_cast<const half8*>(
                reinterpret_cast<const _Float16*>(X) +
                (size_t)sl * SL_HALVES + (size_t)nclamp * 24 + of8 * 8);
        }
        #pragma unroll
        for (int t = 0; t < 6; ++t) {
            half8 a = *reinterpret_cast<const half8*>(
                &BTl[(t * 16 + lm) * 136 + q * 8 + 32 * ks]);
            cf[t] = __builtin_amdgcn_mfma_f32_16x16x32_f16(a, bv, cf[t], 0, 0, 0);
        }
    }

    // Epilogue: D[row=q*4+r][col=lm] = out[feature = t*16+q*4+r][node=lm].
    __half* orow = OUTl + (w * 16 + lm) * 104;
    #pragma unroll
    for (int t = 0; t < 6; ++t) {
        union { int2 i2; __half2 h[2]; } u;
        u.h[0] = __floats2half2_rn(cf[t][0], cf[t][1]);
        u.h[1] = __floats2half2_rn(cf[t][2], cf[t][3]);
        *reinterpret_cast<int2*>(&orow[t * 16 + q * 4]) = u.i2;
    }
    // Same-wave LDS round-trip: sliced fp16 store (chunk c -> slice c/3).
    #pragma unroll
    for (int R = 0; R < 3; ++R) {
        int nl = lane >> 2, c = (lane & 3) + 4 * R;
        int sl = c / 3, of8 = c - sl * 3;
        float4 v = *reinterpret_cast<const float4*>(&OUTl[(w * 16 + nl) * 104 + c * 8]);
        int gn = base + nl;
        if (gn < n) Th4[(size_t)sl * SL_F4 + (size_t)gn * 3 + of8] = v;
    }
}

// ---------------------------------------------------------------------------
// Fused: count (blocks [0,nCB)) + gemm L1 (blocks [nCB, nCB+GB)) — independent.
// ---------------------------------------------------------------------------
__global__ __launch_bounds__(256) void count_gemm1_kernel(
        const int* __restrict__ dst, int* __restrict__ counts4, int* __restrict__ rank,
        int e, const float* __restrict__ X, const __half* __restrict__ BT1,
        float4* __restrict__ Th4, int n, int nCB) {
    if ((int)blockIdx.x < nCB) {
        int i = blockIdx.x * 256 + threadIdx.x;
        if (i < e) rank[i] = atomicAdd(&counts4[dst[i] * 4 + (i & 3)], 1);
    } else {
        mfma_gemm_body<F_INN, float>(X, BT1, Th4, n, blockIdx.x - nCB);
    }
}

template <int FI, typename TIN>
__global__ __launch_bounds__(256) void mfma_gemm_kernel(
        const TIN* __restrict__ X, const __half* __restrict__ BTg,
        float4* __restrict__ Th4, int n) {
    mfma_gemm_body<FI, TIN>(X, BTg, Th4, n, blockIdx.x);
}

// ---------------------------------------------------------------------------
// Weight transpose + fp16: W[K x 96] -> BT[96][136] (pad 8). W1 & W2 together.
// ---------------------------------------------------------------------------
__global__ void wt_kernel(const float* __restrict__ W1, const float* __restrict__ W2,
                          __half* __restrict__ BT1, __half* __restrict__ BT2) {
    int i = blockIdx.x * 256 + threadIdx.x;
    if (i < 96 * 128) {
        int j = i / 128, k = i - j * 128;
        BT1[j * 136 + k] = __float2half(W1[k * 96 + j]);
    } else if (i < 96 * 128 + 96 * 96) {
        int t = i - 96 * 128;
        int j = t / 96, k = t - j * 96;
        BT2[j * 136 + k] = __float2half(W2[k * 96 + j]);
    }
}

// ---------------------------------------------------------------------------
// Scan phase 1: per-block exclusive scan of node degrees; dinv; block sums.
// ---------------------------------------------------------------------------
__global__ __launch_bounds__(1024) void scan_local_kernel(
        const int4* __restrict__ counts4, int* __restrict__ row_start,
        float* __restrict__ dinv, int* __restrict__ blk_sums, int n) {
    __shared__ int wave_sums[16];
    int tid = threadIdx.x, lane = tid & 63, wid = tid >> 6;
    int i = blockIdx.x * 1024 + tid;
    int v = 0;
    if (i < n) {
        int4 c = counts4[i];
        v = c.x + c.y + c.z + c.w;
    }
    int val = v;
    #pragma unroll
    for (int off = 1; off < 64; off <<= 1) {
        int u = __shfl_up(val, off, 64);
        if (lane >= off) val += u;
    }
    if (lane == 63) wave_sums[wid] = val;
    __syncthreads();
    if (wid == 0) {
        int w = (lane < 16) ? wave_sums[lane] : 0;
        #pragma unroll
        for (int off = 1; off < 16; off <<= 1) {
            int u = __shfl_up(w, off, 64);
            if (lane >= off) w += u;
        }
        if (lane < 16) wave_sums[lane] = w;
    }
    __syncthreads();
    int excl = ((wid == 0) ? 0 : wave_sums[wid - 1]) + (val - v);
    if (i < n) {
        row_start[i] = excl;                  // local; global offset in phase 2
        dinv[i] = rsqrtf((float)(v + 1));     // +1 self loop
    }
    if (tid == 0) blk_sums[blockIdx.x] = wave_sums[15];
}

// ---------------------------------------------------------------------------
// Scan phase 2+3 fused: every block redundantly scans the <=64 block sums,
// applies its own offset, emits per-shard bases base4. Block 0 writes total.
// ---------------------------------------------------------------------------
__global__ __launch_bounds__(1024) void scan_apply_kernel(
        int* __restrict__ row_start, const int* __restrict__ blk_sums,
        const int4* __restrict__ counts4, int4* __restrict__ base4, int n, int nblk) {
    __shared__ int s_my, s_tot;
    int tid = threadIdx.x;
    if (tid < 64) {
        int v = (tid < nblk) ? blk_sums[tid] : 0;
        int val = v;
        #pragma unroll
        for (int off = 1; off < 64; off <<= 1) {
            int u = __shfl_up(val, off, 64);
            if (tid >= off) val += u;
        }
        if (tid == (int)blockIdx.x) s_my = val - v;   // exclusive prefix
        if (tid == 63) s_tot = val;                   // grand total == E
    }
    __syncthreads();
    int i = blockIdx.x * 1024 + tid;
    if (i < n) {
        int4 c = counts4[i];
        int b = row_start[i] + s_my;
        row_start[i] = b;
        base4[i] = make_int4(b, b + c.x, b + c.x + c.y, b + c.x + c.y + c.z);
    }
    if (blockIdx.x == 0 && tid == 0) row_start[n] = s_tot;
}

// Atomic-free fill: pos = base4[dst].shard + rank.  One scattered 4B store.
__global__ void fill_csr_kernel(const int* __restrict__ src, const int* __restrict__ dst,
                                const int* __restrict__ rank, const int* __restrict__ base4,
                                int* __restrict__ csr_src, int e) {
    int i = blockIdx.x * blockDim.x + threadIdx.x;
    if (i >= e) return;
    csr_src[base4[dst[i] * 4 + (i & 3)] + rank[i]] = src[i];
}

// ---------------------------------------------------------------------------
// DPP row_shl helper: lane i reads lane i+N within its 16-lane row; 0 if OOB.
// ---------------------------------------------------------------------------
template <int N>
__device__ __forceinline__ float dpp_shl(float x) {
    return __int_as_float(__builtin_amdgcn_update_dpp(
        0, __float_as_int(x), 0x100 + N, 0xF, 0xF, true));
}

// ---------------------------------------------------------------------------
// Sliced aggregation.  Block = one (slice, 16-node group): 4 waves x 4 nodes.
// Per node: 16 lanes = 5 edge slots x 3 chunks (16B each, 48B = slice row)
// + 1 idle.  One gather instruction covers 20 edges.  slice = (bid%8)>>1 so
// each XCD pair's gathers stay inside ONE 2.4MB slice -> L2-resident.
// Slot reduction via DPP row_shl — no LDS, no bank conflicts.
// Self-loop is the virtual position idx-1 with weight dinv[node].
// H[d] = relu(dinv[d]*(sum dinv[s]T[s] + dinv[d]T[d]) + b), fp16 sliced out.
// ---------------------------------------------------------------------------
__global__ __launch_bounds__(256) void agg_kernel(
        const __half* __restrict__ T, const int* __restrict__ row_start,
        const int* __restrict__ csr_src, const float* __restrict__ dinv,
        const float* __restrict__ bias, __half* __restrict__ H, int n) {
    int bid = blockIdx.x;
    int xr = bid & 7, m = bid >> 3;
    int s  = xr >> 1;                       // feature slice 0..3 (one per XCD pair)
    int grp = m * 2 + (xr & 1);             // 16-node group within slice
    if (grp >= NGRP) return;

    int tid = threadIdx.x, lane = tid & 63, wid = tid >> 6;
    int e5 = lane & 15;
    int e  = e5 / 3;                        // edge slot 0..4 (e5==15 -> idle)
    int g  = e5 - e * 3;                    // 16B chunk within 48B slice row
    bool act = e5 < 15;

    int node = grp * 16 + wid * 4 + (lane >> 4);
    float dn = dinv[node];
    int idx = row_start[node], end = row_start[node + 1];
    const _Float16* Ts = reinterpret_cast<const _Float16*>(T) + (size_t)s * SL_HALVES;

    float acc[8];
    #pragma unroll
    for (int t = 0; t < 8; ++t) acc[t] = 0.f;

    auto ROUND = [&](int q) {
        int sn = node; float w = 0.f;
        if (act && q < end) {
            if (q >= idx) { sn = csr_src[q]; w = dinv[sn]; }
            else          { w = dn; }       // q == idx-1: self loop (e==0 only)
        }
        union { half8 v; __half2 h[4]; } u;
        u.v = *reinterpret_cast<const half8*>(Ts + (size_t)sn * 24 + g * 8);
        #pragma unroll
        for (int t = 0; t < 4; ++t) {
            float2 f = __half22float2(u.h[t]);
            acc[2 * t]     = fmaf(w, f.x, acc[2 * t]);
            acc[2 * t + 1] = fmaf(w, f.y, acc[2 * t + 1]);
        }
    };
    int p = idx - 1 + e;
    do { ROUND(p); ROUND(p + 5); p += 10; } while (__any(act && p < end));

    // Reduce the 5 edge slots (stride 3 within each 16-lane row): totals at
    // lanes e5=0..2.  tot = ((s0+s1)+(s2+s3)) + s4.
    float tot[8];
    #pragma unroll
    for (int t = 0; t < 8; ++t) {
        float v1 = acc[t] + dpp_shl<3>(acc[t]);
        float v2 = v1 + dpp_shl<6>(v1);
        tot[t] = v2 + dpp_shl<12>(acc[t]);
    }

    if (e5 < 3) {
        const float4* bp = reinterpret_cast<const float4*>(bias + s * 24 + e5 * 8);
        float4 b0 = bp[0], b1 = bp[1];
        union { int4 i4; __half2 h[4]; } o;
        o.h[0] = __floats2half2_rn(fmaxf(fmaf(dn, tot[0], b0.x), 0.f),
                                   fmaxf(fmaf(dn, tot[1], b0.y), 0.f));
        o.h[1] = __floats2half2_rn(fmaxf(fmaf(dn, tot[2], b0.z), 0.f),
                                   fmaxf(fmaf(dn, tot[3], b0.w), 0.f));
        o.h[2] = __floats2half2_rn(fmaxf(fmaf(dn, tot[4], b1.x), 0.f),
                                   fmaxf(fmaf(dn, tot[5], b1.y), 0.f));
        o.h[3] = __floats2half2_rn(fmaxf(fmaf(dn, tot[6], b1.z), 0.f),
                                   fmaxf(fmaf(dn, tot[7], b1.w), 0.f));
        *reinterpret_cast<int4*>(
            H + (size_t)s * SL_HALVES + (size_t)node * 24 + e5 * 8) = o.i4;
    }
}

// ---------------------------------------------------------------------------
// Output GEMM: out[n x 40] = H[n x 96](fp16, SLICED) @ W[96 x 40] + bias.
// ---------------------------------------------------------------------------
__global__ __launch_bounds__(320) void gemm_out_kernel(
        const __half* __restrict__ A, const float* __restrict__ W,
        const float* __restrict__ bias, float* __restrict__ C, int n) {
    __shared__ float Wlds[96 * 40];
    int tid = threadIdx.y * 10 + threadIdx.x;
    for (int i = tid; i < 96 * 10; i += 320)
        reinterpret_cast<float4*>(Wlds)[i] = reinterpret_cast<const float4*>(W)[i];
    __syncthreads();

    int j    = threadIdx.x * 4;
    int node = blockIdx.x * 32 + threadIdx.y;
    int nc   = min(node, n - 1);
    float4 acc = make_float4(0.f, 0.f, 0.f, 0.f);
    #pragma unroll
    for (int c8 = 0; c8 < 12; ++c8) {            // 8-feature chunk; f = 8*c8
        int sl = c8 / 3, of8 = c8 - sl * 3;      // compile-time (unrolled)
        union { int4 i4; __half2 h[4]; } u;
        u.i4 = *reinterpret_cast<const int4*>(
            A + (size_t)sl * SL_HALVES + (size_t)nc * 24 + of8 * 8);
        #pragma unroll
        for (int t = 0; t < 4; ++t) {
            float2 a = __half22float2(u.h[t]);
            int k = c8 * 8 + 2 * t;
            float4 w0 = *reinterpret_cast<const float4*>(Wlds + k * 40 + j);
            float4 w1 = *reinterpret_cast<const float4*>(Wlds + (k + 1) * 40 + j);
            acc.x += a.x * w0.x + a.y * w1.x;
            acc.y += a.x * w0.y + a.y * w1.y;
            acc.z += a.x * w0.z + a.y * w1.z;
            acc.w += a.x * w0.w + a.y * w1.w;
        }
    }
    if (node < n) {
        float4 b = *reinterpret_cast<const float4*>(bias + j);
        acc.x += b.x; acc.y += b.y; acc.z += b.z; acc.w += b.w;
        *reinterpret_cast<float4*>(C + (size_t)node * 40 + j) = acc;
    }
}

// ---------------------------------------------------------------------------

extern "C" void kernel_launch(void* const* d_in, const int* in_sizes, int n_in,
                              void* d_out, int out_size, void* d_ws, size_t ws_size,
                              hipStream_t stream) {
    const float* x    = (const float*)d_in[0];
    const int*   ei   = (const int*)d_in[1];
    const float* W1   = (const float*)d_in[2];
    const float* b1   = (const float*)d_in[3];
    const float* W2   = (const float*)d_in[4];
    const float* b2   = (const float*)d_in[5];
    const float* Wout = (const float*)d_in[6];
    const float* bout = (const float*)d_in[7];
    float*       out  = (float*)d_out;

    const int* src = ei;            // edge_index[0]
    const int* dst = ei + N_EDGES;  // edge_index[1]

    char* ws = (char*)d_ws;
    size_t off = 0;
    auto alloc = [&](size_t bytes) {
        size_t o = off;
        off = (off + bytes + 511) & ~(size_t)511;
        return (void*)(ws + o);
    };
    int*     counts4   = (int*)    alloc((size_t)N_NODES * 4 * sizeof(int));
    int4*    base4     = (int4*)   alloc((size_t)N_NODES * sizeof(int4));
    int*     row_start = (int*)    alloc((N_NODES + 1) * sizeof(int));
    float*   dinv      = (float*)  alloc(N_NODES * sizeof(float));
    int*     blk_sums  = (int*)    alloc(64 * sizeof(int));
    int*     rank      = (int*)    alloc((size_t)N_EDGES * sizeof(int));
    int*     csr_src   = (int*)    alloc((size_t)N_EDGES * sizeof(int));
    __half*  BT1       = (__half*) alloc((size_t)96 * 136 * sizeof(__half));
    __half*  BT2       = (__half*) alloc((size_t)96 * 136 * sizeof(__half));
    __half*  Th        = (__half*) alloc((size_t)N_NODES * 96 * sizeof(__half));
    __half*  Hh        = (__half*) alloc((size_t)N_NODES * 96 * sizeof(__half));

    const int NSCAN = (N_NODES + 1023) / 1024;   // 49
    const int CB    = (N_EDGES + 255) / 256;     // 3125 count blocks
    const int GB    = (N_NODES + 63) / 64;       // 782 gemm blocks
    const int AGB   = ((NGRP + 1) / 2) * 8;      // 12504 sliced-agg blocks

    // --- prep ---
    hipMemsetAsync(counts4, 0, (size_t)N_NODES * 4 * sizeof(int), stream);
    wt_kernel<<<(96 * 128 + 96 * 96 + 255) / 256, 256, 0, stream>>>(W1, W2, BT1, BT2);

    // --- fused: edge counting + layer-1 GEMM (independent) ---
    count_gemm1_kernel<<<CB + GB, 256, 0, stream>>>(
        dst, counts4, rank, N_EDGES, x, BT1, (float4*)Th, N_NODES, CB);

    // --- scan (2 launches) + fill ---
    scan_local_kernel<<<NSCAN, 1024, 0, stream>>>(
        (const int4*)counts4, row_start, dinv, blk_sums, N_NODES);
    scan_apply_kernel<<<NSCAN, 1024, 0, stream>>>(
        row_start, blk_sums, (const int4*)counts4, base4, N_NODES, NSCAN);
    fill_csr_kernel<<<CB, 256, 0, stream>>>(
        src, dst, rank, (const int*)base4, csr_src, N_EDGES);

    // --- layer 1 aggregation -> H (fp16, sliced) ---
    agg_kernel<<<AGB, 256, 0, stream>>>(
        Th, row_start, csr_src, dinv, b1, Hh, N_NODES);

    // --- layer 2: GEMM (sliced fp16 in/out) + aggregation ---
    mfma_gemm_kernel<F_HID, __half><<<GB, 256, 0, stream>>>(
        Hh, BT2, (float4*)Th, N_NODES);
    agg_kernel<<<AGB, 256, 0, stream>>>(
        Th, row_start, csr_src, dinv, b2, Hh, N_NODES);

    // --- output ---
    gemm_out_kernel<<<(N_NODES + 31) / 32, dim3(10, 32), 0, stream>>>(
        Hh, Wout, bout, out, N_NODES);
}

// Round 4
// 230.133 us; speedup vs baseline: 1.0899x; 1.0899x over previous
//
#include <hip/hip_runtime.h>
#include <hip/hip_fp16.h>

#define N_NODES 50000
#define N_EDGES 800000
#define F_INN   128
#define F_HID   96
#define F_OUTT  40

typedef _Float16 half8 __attribute__((ext_vector_type(8)));
typedef float    floatx4 __attribute__((ext_vector_type(4)));

// ---------------------------------------------------------------------------
// MFMA GEMM body: T[n][96] (fp16, UNSCALED) = X[n x FI] @ W, via 16x16x32 f16.
// A = W^T tile (m=feature), B = node rows (n=node). 4 waves x 16 nodes = 64/blk.
// TIN = float (load+cvt) or __half (direct half8 load).
// LDS: single 26112B buffer; BT tile while computing, then (after a barrier)
// reused as the 13312B OUT staging area -> 6 blocks/CU instead of 4.
// ---------------------------------------------------------------------------
template <int FI, typename TIN>
__device__ __forceinline__ void mfma_gemm_body(
        const TIN* __restrict__ X, const __half* __restrict__ BTg,
        float4* __restrict__ Th4, int n, int bx) {
    __shared__ __half BTl[96 * 136];          // 26112 B; reused as OUT staging
    __half* OUTl = BTl;                       // [4*16][104] after the barrier
    int tid = threadIdx.x;
    {   // stage BT (1632 x 16B)
        const int4* s = reinterpret_cast<const int4*>(BTg);
        int4* d = reinterpret_cast<int4*>(BTl);
        for (int i = tid; i < 96 * 136 / 8; i += 256) d[i] = s[i];
    }
    __syncthreads();

    int lane = tid & 63, w = tid >> 6;
    int lm = lane & 15, q = lane >> 4;
    int base = bx * 64 + w * 16;
    int node = base + lm;
    int nclamp = min(node, n - 1);
    const TIN* Xrow = X + (size_t)nclamp * FI;

    floatx4 cf[6];
    #pragma unroll
    for (int t = 0; t < 6; ++t) cf[t] = (floatx4){0.f, 0.f, 0.f, 0.f};

    constexpr int KS = FI / 32;
    #pragma unroll
    for (int ks = 0; ks < KS; ++ks) {
        // B-operand: lane holds k = 32*ks + q*8 .. +7 of this node's row
        half8 bv;
        if constexpr (sizeof(TIN) == 4) {
            const float4* xr = reinterpret_cast<const float4*>(Xrow + 32 * ks + q * 8);
            float4 f0 = xr[0], f1 = xr[1];
            union { half8 v; __half2 h[4]; } b;
            b.h[0] = __floats2half2_rn(f0.x, f0.y);
            b.h[1] = __floats2half2_rn(f0.z, f0.w);
            b.h[2] = __floats2half2_rn(f1.x, f1.y);
            b.h[3] = __floats2half2_rn(f1.z, f1.w);
            bv = b.v;
        } else {
            bv = *reinterpret_cast<const half8*>(Xrow + 32 * ks + q * 8);
        }
        #pragma unroll
        for (int t = 0; t < 6; ++t) {
            half8 a = *reinterpret_cast<const half8*>(
                &BTl[(t * 16 + lm) * 136 + q * 8 + 32 * ks]);
            cf[t] = __builtin_amdgcn_mfma_f32_16x16x32_f16(a, bv, cf[t], 0, 0, 0);
        }
    }

    __syncthreads();   // all waves done reading BTl; safe to reuse as OUTl

    // Epilogue: D[row=q*4+r][col=lm] = out[feature = t*16+q*4+r][node=lm].
    __half* orow = OUTl + (w * 16 + lm) * 104;
    #pragma unroll
    for (int t = 0; t < 6; ++t) {
        union { int2 i2; __half2 h[2]; } u;
        u.h[0] = __floats2half2_rn(cf[t][0], cf[t][1]);
        u.h[1] = __floats2half2_rn(cf[t][2], cf[t][3]);
        *reinterpret_cast<int2*>(&orow[t * 16 + q * 4]) = u.i2;
    }
    // Same-wave LDS round-trip: coalesced fp16 row store (12 x float4 per node).
    #pragma unroll
    for (int R = 0; R < 3; ++R) {
        int nl = lane >> 2, c = (lane & 3) + 4 * R;
        float4 v = *reinterpret_cast<const float4*>(&OUTl[(w * 16 + nl) * 104 + c * 8]);
        int gn = base + nl;
        if (gn < n) Th4[(size_t)gn * 12 + c] = v;
    }
}

// ---------------------------------------------------------------------------
// Fused: count (blocks [0,nCB)) + gemm L1 (blocks [nCB, nCB+GB)) — independent.
// Count phase: 2 edges/thread -> two independent atomicAdds in flight, half
// the exposed round-trip latency.
// ---------------------------------------------------------------------------
__global__ __launch_bounds__(256) void count_gemm1_kernel(
        const int* __restrict__ dst, int* __restrict__ counts4, int* __restrict__ rank,
        int e, const float* __restrict__ X, const __half* __restrict__ BT1,
        float4* __restrict__ Th4, int n, int nCB) {
    if ((int)blockIdx.x < nCB) {
        int i = blockIdx.x * 512 + threadIdx.x;
        int j = i + 256;
        int di = 0, dj = 0, ri, rj;
        bool bi = i < e, bj = j < e;
        if (bi) di = dst[i];
        if (bj) dj = dst[j];
        if (bi) ri = atomicAdd(&counts4[di * 4 + (i & 3)], 1);
        if (bj) rj = atomicAdd(&counts4[dj * 4 + (j & 3)], 1);
        if (bi) rank[i] = ri;
        if (bj) rank[j] = rj;
    } else {
        mfma_gemm_body<F_INN, float>(X, BT1, Th4, n, blockIdx.x - nCB);
    }
}

template <int FI, typename TIN>
__global__ __launch_bounds__(256) void mfma_gemm_kernel(
        const TIN* __restrict__ X, const __half* __restrict__ BTg,
        float4* __restrict__ Th4, int n) {
    mfma_gemm_body<FI, TIN>(X, BTg, Th4, n, blockIdx.x);
}

// ---------------------------------------------------------------------------
// Weight transpose + fp16: W[K x 96] -> BT[96][136] (pad 8). W1 & W2 together.
// ---------------------------------------------------------------------------
__global__ void wt_kernel(const float* __restrict__ W1, const float* __restrict__ W2,
                          __half* __restrict__ BT1, __half* __restrict__ BT2) {
    int i = blockIdx.x * 256 + threadIdx.x;
    if (i < 96 * 128) {
        int j = i / 128, k = i - j * 128;
        BT1[j * 136 + k] = __float2half(W1[k * 96 + j]);
    } else if (i < 96 * 128 + 96 * 96) {
        int t = i - 96 * 128;
        int j = t / 96, k = t - j * 96;
        BT2[j * 136 + k] = __float2half(W2[k * 96 + j]);
    }
}

// ---------------------------------------------------------------------------
// Scan phase 1: per-block exclusive scan of node degrees; dinv; block sums.
// ---------------------------------------------------------------------------
__global__ __launch_bounds__(1024) void scan_local_kernel(
        const int4* __restrict__ counts4, int* __restrict__ row_start,
        float* __restrict__ dinv, int* __restrict__ blk_sums, int n) {
    __shared__ int wave_sums[16];
    int tid = threadIdx.x, lane = tid & 63, wid = tid >> 6;
    int i = blockIdx.x * 1024 + tid;
    int v = 0;
    if (i < n) {
        int4 c = counts4[i];
        v = c.x + c.y + c.z + c.w;
    }
    int val = v;
    #pragma unroll
    for (int off = 1; off < 64; off <<= 1) {
        int u = __shfl_up(val, off, 64);
        if (lane >= off) val += u;
    }
    if (lane == 63) wave_sums[wid] = val;
    __syncthreads();
    if (wid == 0) {
        int w = (lane < 16) ? wave_sums[lane] : 0;
        #pragma unroll
        for (int off = 1; off < 16; off <<= 1) {
            int u = __shfl_up(w, off, 64);
            if (lane >= off) w += u;
        }
        if (lane < 16) wave_sums[lane] = w;
    }
    __syncthreads();
    int excl = ((wid == 0) ? 0 : wave_sums[wid - 1]) + (val - v);
    if (i < n) {
        row_start[i] = excl;                  // local; global offset in phase 2
        dinv[i] = rsqrtf((float)(v + 1));     // +1 self loop
    }
    if (tid == 0) blk_sums[blockIdx.x] = wave_sums[15];
}

// ---------------------------------------------------------------------------
// Scan phase 2+3 fused: every block redundantly scans the <=64 block sums,
// applies its own offset, emits per-shard bases base4. Block 0 writes total.
// ---------------------------------------------------------------------------
__global__ __launch_bounds__(1024) void scan_apply_kernel(
        int* __restrict__ row_start, const int* __restrict__ blk_sums,
        const int4* __restrict__ counts4, int4* __restrict__ base4, int n, int nblk) {
    __shared__ int s_my, s_tot;
    int tid = threadIdx.x;
    if (tid < 64) {
        int v = (tid < nblk) ? blk_sums[tid] : 0;
        int val = v;
        #pragma unroll
        for (int off = 1; off < 64; off <<= 1) {
            int u = __shfl_up(val, off, 64);
            if (tid >= off) val += u;
        }
        if (tid == (int)blockIdx.x) s_my = val - v;   // exclusive prefix
        if (tid == 63) s_tot = val;                   // grand total == E
    }
    __syncthreads();
    int i = blockIdx.x * 1024 + tid;
    if (i < n) {
        int4 c = counts4[i];
        int b = row_start[i] + s_my;
        row_start[i] = b;
        base4[i] = make_int4(b, b + c.x, b + c.x + c.y, b + c.x + c.y + c.z);
    }
    if (blockIdx.x == 0 && tid == 0) row_start[n] = s_tot;
}

// Atomic-free fill: pos = base4[dst].shard + rank.  One scattered 4B store.
__global__ void fill_csr_kernel(const int* __restrict__ src, const int* __restrict__ dst,
                                const int* __restrict__ rank, const int* __restrict__ base4,
                                int* __restrict__ csr_src, int e) {
    int i = blockIdx.x * blockDim.x + threadIdx.x;
    if (i >= e) return;
    csr_src[base4[dst[i] * 4 + (i & 3)] + rank[i]] = src[i];
}

// ---------------------------------------------------------------------------
// Aggregation: one wave per node; T unscaled fp16; per-edge weight dinv[s] is
// a wave-uniform SCALAR load.  H[d] = relu(dinv[d]*(Σ dinv[s]T[s] + dinv[d]T[d]) + b)
// Output fp16.
// ---------------------------------------------------------------------------
__global__ __launch_bounds__(256) void agg_kernel(
        const __half2* __restrict__ T, const int* __restrict__ row_start,
        const int* __restrict__ csr_src, const float* __restrict__ dinv,
        const float* __restrict__ bias, __half2* __restrict__ H, int n) {
    int lane = threadIdx.x & 63;
    int node = __builtin_amdgcn_readfirstlane(blockIdx.x * 4 + (threadIdx.x >> 6));
    if (node >= n) return;
    int fl = min(lane, 47);                    // lanes 48..63 duplicate lane 47

    float dn = dinv[node];
    float2 self = __half22float2(T[(size_t)node * 48 + fl]);
    float accx = dn * self.x, accy = dn * self.y;   // dinv[d]*T[d]

    int idx = row_start[node];
    int end = row_start[node + 1];
    for (; idx + 8 <= end; idx += 8) {
        int s[8];
        #pragma unroll
        for (int u = 0; u < 8; ++u) s[u] = csr_src[idx + u];
        float ws[8];
        #pragma unroll
        for (int u = 0; u < 8; ++u) ws[u] = dinv[s[u]];          // scalar loads
        float2 f[8];
        #pragma unroll
        for (int u = 0; u < 8; ++u) f[u] = __half22float2(T[(size_t)s[u] * 48 + fl]);
        #pragma unroll
        for (int u = 0; u < 8; ++u) {
            accx = fmaf(ws[u], f[u].x, accx);
            accy = fmaf(ws[u], f[u].y, accy);
        }
    }
    for (; idx < end; ++idx) {
        int s = csr_src[idx];
        float w = dinv[s];
        float2 f = __half22float2(T[(size_t)s * 48 + fl]);
        accx = fmaf(w, f.x, accx);
        accy = fmaf(w, f.y, accy);
    }
    if (lane < 48) {
        float2 b = reinterpret_cast<const float2*>(bias)[lane];
        float ox = fmaxf(fmaf(dn, accx, b.x), 0.f);
        float oy = fmaxf(fmaf(dn, accy, b.y), 0.f);
        H[(size_t)node * 48 + lane] = __floats2half2_rn(ox, oy);
    }
}

// ---------------------------------------------------------------------------
// Output GEMM: out[n x 40] = H[n x 96](fp16) @ W[96 x 40] + bias (fp32 acc).
// ---------------------------------------------------------------------------
__global__ __launch_bounds__(320) void gemm_out_kernel(
        const __half2* __restrict__ A, const float* __restrict__ W,
        const float* __restrict__ bias, float* __restrict__ C, int n) {
    __shared__ float Wlds[96 * 40];
    int tid = threadIdx.y * 10 + threadIdx.x;
    for (int i = tid; i < 96 * 10; i += 320)
        reinterpret_cast<float4*>(Wlds)[i] = reinterpret_cast<const float4*>(W)[i];
    __syncthreads();

    int j    = threadIdx.x * 4;
    int node = blockIdx.x * 32 + threadIdx.y;
    int nc   = min(node, n - 1);
    const __half2* Ah = A + (size_t)nc * 48;
    float4 acc = make_float4(0.f, 0.f, 0.f, 0.f);
    for (int k2 = 0; k2 < 48; k2 += 2) {          // k = 2*k2 .. 2*k2+3
        float2 a01 = __half22float2(Ah[k2]);
        float2 a23 = __half22float2(Ah[k2 + 1]);
        int k = 2 * k2;
        float4 w0 = *reinterpret_cast<const float4*>(Wlds + (k + 0) * 40 + j);
        float4 w1 = *reinterpret_cast<const float4*>(Wlds + (k + 1) * 40 + j);
        float4 w2 = *reinterpret_cast<const float4*>(Wlds + (k + 2) * 40 + j);
        float4 w3 = *reinterpret_cast<const float4*>(Wlds + (k + 3) * 40 + j);
        acc.x += a01.x * w0.x + a01.y * w1.x + a23.x * w2.x + a23.y * w3.x;
        acc.y += a01.x * w0.y + a01.y * w1.y + a23.x * w2.y + a23.y * w3.y;
        acc.z += a01.x * w0.z + a01.y * w1.z + a23.x * w2.z + a23.y * w3.z;
        acc.w += a01.x * w0.w + a01.y * w1.w + a23.x * w2.w + a23.y * w3.w;
    }
    if (node < n) {
        float4 b = *reinterpret_cast<const float4*>(bias + j);
        acc.x += b.x; acc.y += b.y; acc.z += b.z; acc.w += b.w;
        *reinterpret_cast<float4*>(C + (size_t)node * 40 + j) = acc;
    }
}

// ---------------------------------------------------------------------------

extern "C" void kernel_launch(void* const* d_in, const int* in_sizes, int n_in,
                              void* d_out, int out_size, void* d_ws, size_t ws_size,
                              hipStream_t stream) {
    const float* x    = (const float*)d_in[0];
    const int*   ei   = (const int*)d_in[1];
    const float* W1   = (const float*)d_in[2];
    const float* b1   = (const float*)d_in[3];
    const float* W2   = (const float*)d_in[4];
    const float* b2   = (const float*)d_in[5];
    const float* Wout = (const float*)d_in[6];
    const float* bout = (const float*)d_in[7];
    float*       out  = (float*)d_out;

    const int* src = ei;            // edge_index[0]
    const int* dst = ei + N_EDGES;  // edge_index[1]

    char* ws = (char*)d_ws;
    size_t off = 0;
    auto alloc = [&](size_t bytes) {
        size_t o = off;
        off = (off + bytes + 511) & ~(size_t)511;
        return (void*)(ws + o);
    };
    int*     counts4   = (int*)    alloc((size_t)N_NODES * 4 * sizeof(int));
    int4*    base4     = (int4*)   alloc((size_t)N_NODES * sizeof(int4));
    int*     row_start = (int*)    alloc((N_NODES + 1) * sizeof(int));
    float*   dinv      = (float*)  alloc(N_NODES * sizeof(float));
    int*     blk_sums  = (int*)    alloc(64 * sizeof(int));
    int*     rank      = (int*)    alloc((size_t)N_EDGES * sizeof(int));
    int*     csr_src   = (int*)    alloc((size_t)N_EDGES * sizeof(int));
    __half*  BT1       = (__half*) alloc((size_t)96 * 136 * sizeof(__half));
    __half*  BT2       = (__half*) alloc((size_t)96 * 136 * sizeof(__half));
    __half2* Th        = (__half2*)alloc((size_t)N_NODES * 48 * sizeof(__half2));
    __half2* Hh        = (__half2*)alloc((size_t)N_NODES * 48 * sizeof(__half2));

    const int NSCAN = (N_NODES + 1023) / 1024;   // 49
    const int CB2   = (N_EDGES + 511) / 512;     // 1563 count blocks (2 edges/thr)
    const int FB    = (N_EDGES + 255) / 256;     // 3125 fill blocks
    const int GB    = (N_NODES + 63) / 64;       // 782 gemm blocks

    // --- prep ---
    hipMemsetAsync(counts4, 0, (size_t)N_NODES * 4 * sizeof(int), stream);
    wt_kernel<<<(96 * 128 + 96 * 96 + 255) / 256, 256, 0, stream>>>(W1, W2, BT1, BT2);

    // --- fused: edge counting + layer-1 GEMM (independent) ---
    count_gemm1_kernel<<<CB2 + GB, 256, 0, stream>>>(
        dst, counts4, rank, N_EDGES, x, BT1, (float4*)Th, N_NODES, CB2);

    // --- scan (2 launches) + fill ---
    scan_local_kernel<<<NSCAN, 1024, 0, stream>>>(
        (const int4*)counts4, row_start, dinv, blk_sums, N_NODES);
    scan_apply_kernel<<<NSCAN, 1024, 0, stream>>>(
        row_start, blk_sums, (const int4*)counts4, base4, N_NODES, NSCAN);
    fill_csr_kernel<<<FB, 256, 0, stream>>>(
        src, dst, rank, (const int*)base4, csr_src, N_EDGES);

    // --- layer 1 aggregation -> H (fp16) ---
    agg_kernel<<<(N_NODES + 3) / 4, 256, 0, stream>>>(
        Th, row_start, csr_src, dinv, b1, Hh, N_NODES);

    // --- layer 2: GEMM (fp16 in) + aggregation ---
    mfma_gemm_kernel<F_HID, __half><<<GB, 256, 0, stream>>>(
        (const __half*)Hh, BT2, (float4*)Th, N_NODES);
    agg_kernel<<<(N_NODES + 3) / 4, 256, 0, stream>>>(
        Th, row_start, csr_src, dinv, b2, Hh, N_NODES);

    // --- output ---
    gemm_out_kernel<<<(N_NODES + 31) / 32, dim3(10, 32), 0, stream>>>(
        Hh, Wout, bout, out, N_NODES);
}